// Round 4
// baseline (503.081 us; speedup 1.0000x reference)
//
#include <hip/hip_runtime.h>

typedef unsigned short ushort_t;
typedef __attribute__((ext_vector_type(4))) float float4_t;
typedef __attribute__((ext_vector_type(8))) short short8_t;
typedef __attribute__((ext_vector_type(8))) unsigned short ushort8_t;

// fp32 -> bf16 round-to-nearest-even (raw bits)
__device__ __forceinline__ ushort_t f2bf(float f) {
    unsigned u = __builtin_bit_cast(unsigned, f);
    u = (u + 0x7fffu + ((u >> 16) & 1u)) >> 16;
    return (ushort_t)u;
}

// async global->LDS, 16B per lane; lds dest is wave-uniform base (HW adds lane*16)
__device__ __forceinline__ void gld16(const void* g, void* l) {
    __builtin_amdgcn_global_load_lds(
        (const __attribute__((address_space(1))) unsigned int*)g,
        (__attribute__((address_space(3))) unsigned int*)l, 16, 0, 0);
}

// ---------------------------------------------------------------------------
// ws layout (bytes):
//   xn  [16][130][130][128] bf16  @ 0          NHWC + 1px zero halo
//   w2  [16][9][128][128]  bf16   @ 69222400   per-sample weights
//   p   [16][128] f32             @ 73940992   routing avgpool
//   cp  [16][128] f32             @ 73949184   SE channel sums (raw)
//   rwt [16][16]  f32             @ 73957376   softmax routing weights
//   cw  [16][128] f32             @ 73958400   SE sigmoid weights
//   sp  [16][2][134][134] f32     @ 73966592   spatial stats, 3px zero halo
// ---------------------------------------------------------------------------

__global__ __launch_bounds__(256) void init_kernel(float* __restrict__ p, float* __restrict__ cp,
                                                   float* __restrict__ sp, ushort_t* __restrict__ xn) {
    int t = blockIdx.x * 256 + threadIdx.x;
    if (t < 2048) { p[t] = 0.f; return; }
    if (t < 4096) { cp[t - 2048] = 0.f; return; }
    if (t < 4096 + 574592) { sp[t - 4096] = 0.f; return; }
    int e = t - (4096 + 574592);
    if (e < 1056768) {                 // 16 * 516 * 128 halo elements
        int b = e / 66048;             // 516*128
        int r = e % 66048;
        int pix = r >> 7, i = r & 127;
        int hp, wp;
        if (pix < 130)      { hp = 0;   wp = pix; }
        else if (pix < 260) { hp = 129; wp = pix - 130; }
        else { int q = pix - 260; hp = 1 + (q >> 1); wp = (q & 1) ? 129 : 0; }
        xn[((b * 130 + hp) * 130 + wp) * 128 + i] = 0;
    }
}

// NCHW fp32 -> NHWC bf16 (haloed), fused routing avg-pool partial sums.
__global__ __launch_bounds__(256) void transpose_kernel(const float* __restrict__ x,
                                                        ushort_t* __restrict__ xn,
                                                        float* __restrict__ p) {
    __shared__ float tile[128][65];
    int blk = blockIdx.x;
    int wt = blk & 1, h = (blk >> 1) & 127, b = blk >> 8;
    int w0 = wt * 64;
    int tid = threadIdx.x;
    int wl = tid & 63, ig = tid >> 6;
    const float* src = x + ((long)(b * 128) * 128 + h) * 128 + w0 + wl;  // x[b][i][h][w]
    #pragma unroll
    for (int i = ig; i < 128; i += 4) tile[i][wl] = src[(long)i * 16384];
    __syncthreads();
    if (tid < 128) {   // routing avgpool partials (fp32, pre-quantization)
        float s = 0.f;
        #pragma unroll
        for (int w = 0; w < 64; ++w) s += tile[tid][w];
        atomicAdd(&p[b * 128 + tid], s * (1.0f / 16384.0f));
    }
    int l16 = tid & 15, wq = tid >> 4;
    #pragma unroll
    for (int pass = 0; pass < 4; ++pass) {
        int w = wq + pass * 16;
        ushort8_t v;
        #pragma unroll
        for (int j = 0; j < 8; ++j) v[j] = f2bf(tile[l16 * 8 + j][w]);
        *(ushort8_t*)&xn[((b * 130 + h + 1) * 130 + (w0 + w + 1)) * 128 + l16 * 8] = v;
    }
}

// routing MLP
__global__ __launch_bounds__(256) void routing_kernel(const float* __restrict__ p,
        const float* __restrict__ rw1, const float* __restrict__ g1, const float* __restrict__ b1,
        const float* __restrict__ rw2, const float* __restrict__ g2, const float* __restrict__ b2,
        const float* __restrict__ rw3, const float* __restrict__ rb3, float* __restrict__ rwt) {
    __shared__ float sh[16][16];
    __shared__ float sg[16][128];
    __shared__ float sl[16][16];
    int tid = threadIdx.x;
    const float bns = rsqrtf(1.0f + 1e-5f);
    {   int b = tid >> 4, j = tid & 15;
        float s = 0.f;
        for (int i = 0; i < 128; ++i) s += p[b * 128 + i] * rw1[j * 128 + i];
        s = s * (g1[j] * bns) + b1[j];
        sh[b][j] = fmaxf(s, 0.f); }
    __syncthreads();
    for (int c = 0; c < 8; ++c) {
        int idx = tid + c * 256;
        int b = idx >> 7, j = idx & 127;
        float s = 0.f;
        for (int k = 0; k < 16; ++k) s += sh[b][k] * rw2[j * 16 + k];
        s = s * (g2[j] * bns) + b2[j];
        sg[b][j] = 1.0f / (1.0f + expf(-s));
    }
    __syncthreads();
    {   int b = tid >> 4, e = tid & 15;
        float s = rb3[e];
        for (int j = 0; j < 128; ++j) s += sg[b][j] * rw3[e * 128 + j];
        sl[b][e] = s; }
    __syncthreads();
    {   int b = tid >> 4, e = tid & 15;
        float m = -1e30f;
        for (int k = 0; k < 16; ++k) m = fmaxf(m, sl[b][k]);
        float num = expf(sl[b][e] - m), den = 0.f;
        for (int k = 0; k < 16; ++k) den += expf(sl[b][k] - m);
        rwt[b * 16 + e] = num / den; }
}

// w2[b][dydx][o][i] = sum_e rwt[b][e] * experts[e][o][i][dydx]  (bf16 out)
// 256 threads: split experts 8+8, LDS combine.
__global__ __launch_bounds__(256) void wgen_kernel(const float* __restrict__ experts,
                                                   const float* __restrict__ rwt,
                                                   ushort_t* __restrict__ w2) {
    int b = blockIdx.x >> 7, o = blockIdx.x & 127;
    int tid = threadIdx.x;
    int i = tid & 127, eh = tid >> 7;
    __shared__ float rw[16];
    __shared__ float part[9][128];
    if (tid < 16) rw[tid] = rwt[b * 16 + tid];
    __syncthreads();
    float acc[9] = {0, 0, 0, 0, 0, 0, 0, 0, 0};
    const float* ep = experts + (long)(eh * 8) * 147456 + (o * 128 + i) * 9;
    #pragma unroll
    for (int e = 0; e < 8; ++e) {
        float r = rw[eh * 8 + e];
        const float* q = ep + (long)e * 147456;
        #pragma unroll
        for (int d = 0; d < 9; ++d) acc[d] += r * q[d];
    }
    if (eh) {
        #pragma unroll
        for (int d = 0; d < 9; ++d) part[d][i] = acc[d];
    }
    __syncthreads();
    if (!eh) {
        #pragma unroll
        for (int d = 0; d < 9; ++d)
            w2[((b * 9 + d) << 14) + (o << 7) + i] = f2bf(acc[d] + part[d][i]);
    }
}

// Per-sample conv as MFMA implicit GEMM -- TWO output rows per block.
// 512 thr (8 waves, wave tile 32o x 64w x 2rows), grid 1024 = b(16) x hpair(64).
// All 4 haloed X rows staged ONCE in prologue (no mid-loop X restage, no full
// drains). A chunks (8KB = [128o][32i] for one (dy,dx,ic)) ring-3 buffered,
// exactly 1 gld16/wave/chunk -> exact vmcnt(1) per iteration.
// B-frag reuse: chunk order (dx,ic) outer, dy inner; B(X[k]) serves row0@dy=k
// and row1@dy=k-1 -> 4 ping-pong bfr register sets, reads/MFMA 0.5 -> 0.458.
// A-DMA + barrier count per output row halved vs 1-row blocks.
// LDS = 4*33280 (X) + 3*8192 (A) = 157696 B -> 1 block/CU (8 waves = 2/SIMD).
struct __align__(16) ConvSmem {
    union {
        struct { ushort_t X[4][16640]; ushort_t A[3][4096]; } t;
        float c[4224];   // epilogue staging: 32 rows x 132 (padded) fp32
    };
};

__global__ __launch_bounds__(512, 2) void conv_kernel(const ushort_t* __restrict__ xn,
                                                      const ushort_t* __restrict__ w2,
                                                      float* __restrict__ out,
                                                      float* __restrict__ cp) {
    __shared__ ConvSmem sm;
    // XCD-aware swizzle (1024 % 8 == 0 -> bijective)
    int bh = (blockIdx.x & 7) * 128 + (blockIdx.x >> 3);
    int b = bh >> 6, h0 = (bh & 63) * 2;
    int tid = threadIdx.x;
    int lane = tid & 63, wave = tid >> 6;
    int wo = wave >> 1, ww = wave & 1;       // 4 o-quarters x 2 w-halves
    int q = lane >> 4, nl = lane & 15;

    float4_t acc[2][2][4];                    // [row][mi][ni]
    #pragma unroll
    for (int r = 0; r < 2; ++r)
        #pragma unroll
        for (int mi = 0; mi < 2; ++mi)
            #pragma unroll
            for (int ni = 0; ni < 4; ++ni) acc[r][mi][ni] = (float4_t){0.f, 0.f, 0.f, 0.f};

    const ushort_t* xbase = xn + (b * 130 + h0) * 16640;   // haloed rows h0..h0+3
    const ushort_t* abase = w2 + (long)b * 147456;

    // ---- prologue: stage all 4 X rows (132 segs across 8 waves) ----
    for (int s = wave; s < 132; s += 8) {
        int r = s / 33, seg = s - r * 33;
        if (seg < 32 || lane < 32) {
            int lofs = seg * 512 + lane * 8;
            int pp = lofs >> 7, jb = (lofs & 127) >> 3;
            gld16(xbase + r * 16640 + (pp << 7) + ((jb ^ (pp & 15)) << 3),
                  &sm.t.X[r][seg * 512]);
        }
    }

    auto stageA = [&](int c) {   // chunk c = g*3 + t, g = dx*4+ic; 1 gld16/wave
        int g = c / 3, t = c - g * 3;
        int dx = g >> 2, ic = g & 3;
        const ushort_t* ab = abase + (t * 3 + dx) * 16384 + ic * 32;
        int o = wave * 16 + (lane >> 2);
        int jsrc = (lane & 3) ^ ((o >> 1) & 3);   // bank-spread swizzle
        gld16(ab + o * 128 + (jsrc << 3), &sm.t.A[c % 3][wave * 512]);
    };

    short8_t bfr[2][2][4];   // slot [k&1][k>>1]; holds B(X[k]) for current group
    auto bfrRead = [&](int k, int dx, int ic) {
        int J = ic * 4 + q;
        #pragma unroll
        for (int ni = 0; ni < 4; ++ni) {
            int pp = ww * 64 + ni * 16 + nl + dx;
            bfr[k & 1][k >> 1][ni] =
                *(const short8_t*)&sm.t.X[k][(pp << 7) + ((J ^ (pp & 15)) << 3)];
        }
    };
    auto bfrAhead = [&](int c) {   // read the NEW X-row frags chunk c needs
        int g = c / 3, t = c - g * 3;
        int dx = g >> 2, ic = g & 3;
        if (t == 0) { bfrRead(0, dx, ic); bfrRead(1, dx, ic); }
        else if (t == 1) bfrRead(2, dx, ic);
        else bfrRead(3, dx, ic);
    };

    stageA(0); stageA(1);
    asm volatile("s_waitcnt vmcnt(0)" ::: "memory");
    __builtin_amdgcn_s_barrier();
    bfrAhead(0);

    #pragma unroll
    for (int c = 0; c < 36; ++c) {
        if (c + 2 < 36) stageA(c + 2);          // ring-3, prefetch distance 2
        // afr for THIS chunk (A(c) guaranteed by prev iter's vmcnt+barrier)
        short8_t afr[2];
        const ushort_t* ap = sm.t.A[c % 3];
        #pragma unroll
        for (int mi = 0; mi < 2; ++mi) {
            int o = wo * 32 + mi * 16 + nl;
            afr[mi] = *(const short8_t*)&ap[(o << 5) + ((q ^ ((o >> 1) & 3)) << 3)];
        }
        if (c + 1 < 36) bfrAhead(c + 1);        // X-only reads, run under MFMAs
        const int t = c % 3;
        const int kA = t, kB = t + 1;           // row0 uses X[t], row1 uses X[t+1]
        __builtin_amdgcn_s_setprio(1);
        #pragma unroll
        for (int mi = 0; mi < 2; ++mi)
            #pragma unroll
            for (int ni = 0; ni < 4; ++ni) {
                acc[0][mi][ni] = __builtin_amdgcn_mfma_f32_16x16x32_bf16(
                    afr[mi], bfr[kA & 1][kA >> 1][ni], acc[0][mi][ni], 0, 0, 0);
                acc[1][mi][ni] = __builtin_amdgcn_mfma_f32_16x16x32_bf16(
                    afr[mi], bfr[kB & 1][kB >> 1][ni], acc[1][mi][ni], 0, 0, 0);
            }
        __builtin_amdgcn_s_setprio(0);
        // counted waits: ensure A(c+1) complete for next iter's afr; never a
        // full drain in steady state (tail c=34 drains the single in-flight).
        if (c <= 33)      asm volatile("s_waitcnt vmcnt(1)" ::: "memory");
        else if (c == 34) asm volatile("s_waitcnt vmcnt(0)" ::: "memory");
        if (c < 35) __builtin_amdgcn_s_barrier();
    }

    // SE channel sums: combine both rows, shuffle-reduce, one atomic per o
    #pragma unroll
    for (int mi = 0; mi < 2; ++mi) {
        int o0 = wo * 32 + mi * 16 + q * 4;
        float rs[4] = {0.f, 0.f, 0.f, 0.f};
        #pragma unroll
        for (int r = 0; r < 2; ++r)
            #pragma unroll
            for (int ni = 0; ni < 4; ++ni) {
                float4_t v = acc[r][mi][ni];
                #pragma unroll
                for (int rr = 0; rr < 4; ++rr) rs[rr] += v[rr];
            }
        #pragma unroll
        for (int rr = 0; rr < 4; ++rr) {
            for (int msk = 1; msk < 16; msk <<= 1) rs[rr] += __shfl_xor(rs[rr], msk, 64);
            if (nl == 0) atomicAdd(&cp[(b << 7) + o0 + rr], rs[rr]);
        }
    }

    // C store via LDS slices -> full-line coalesced writes; 2 rows x 4 o-slices
    #pragma unroll
    for (int r = 0; r < 2; ++r) {
        #pragma unroll
        for (int os = 0; os < 4; ++os) {
            __syncthreads();   // prior readers done (also first-time: K-loop LDS)
            if (wo == os) {
                #pragma unroll
                for (int mi = 0; mi < 2; ++mi)
                    #pragma unroll
                    for (int ni = 0; ni < 4; ++ni) {
                        float4_t v = acc[r][mi][ni];
                        int orow = mi * 16 + q * 4;
                        int w = ww * 64 + ni * 16 + nl;
                        #pragma unroll
                        for (int rr = 0; rr < 4; ++rr) sm.c[(orow + rr) * 132 + w] = v[rr];
                    }
            }
            __syncthreads();
            int row = tid >> 4, j = tid & 15;
            float* og = out + (((long)((b << 7) + os * 32 + row)) << 14) + ((h0 + r) << 7) + j * 8;
            *(float4_t*)og = *(const float4_t*)&sm.c[row * 132 + j * 8];
            *(float4_t*)(og + 4) = *(const float4_t*)&sm.c[row * 132 + j * 8 + 4];
        }
    }
}

// SE MLP
__global__ __launch_bounds__(256) void se_kernel(const float* __restrict__ cp,
        const float* __restrict__ w1, const float* __restrict__ g1, const float* __restrict__ b1,
        const float* __restrict__ w2, const float* __restrict__ g2, const float* __restrict__ b2,
        float* __restrict__ cw) {
    __shared__ float sc[16][128];
    __shared__ float sh[16][16];
    int tid = threadIdx.x;
    const float bns = rsqrtf(1.0f + 1e-5f);
    for (int c = 0; c < 8; ++c) {
        int idx = tid + c * 256;
        sc[idx >> 7][idx & 127] = cp[idx] * (1.0f / 16384.0f);
    }
    __syncthreads();
    {   int b = tid >> 4, j = tid & 15;
        float s = 0.f;
        for (int o = 0; o < 128; ++o) s += sc[b][o] * w1[j * 128 + o];
        s = s * (g1[j] * bns) + b1[j];
        sh[b][j] = fmaxf(s, 0.f); }
    __syncthreads();
    for (int c = 0; c < 8; ++c) {
        int idx = tid + c * 256;
        int b = idx >> 7, o = idx & 127;
        float s = 0.f;
        for (int k = 0; k < 16; ++k) s += sh[b][k] * w2[o * 16 + k];
        s = s * (g2[o] * bns) + b2[o];
        cw[idx] = 1.0f / (1.0f + expf(-s));
    }
}

// spatial stats of out*cw: mean & max over channels -> sp (3px haloed)
__global__ __launch_bounds__(256) void stat_kernel(const float* __restrict__ out,
                                                   const float* __restrict__ cw,
                                                   float* __restrict__ sp) {
    int b = blockIdx.x >> 7, h = blockIdx.x & 127;
    int tid = threadIdx.x;
    int w = tid & 127, oh = tid >> 7;
    __shared__ float scw[128], ssum[128], smax[128];
    if (tid < 128) scw[tid] = cw[(b << 7) + tid];
    __syncthreads();
    const float* src = out + ((long)b << 21) + ((long)(oh * 64) << 14) + (h << 7) + w;
    float s = 0.f, m = -1e30f;
    #pragma unroll 8
    for (int o = 0; o < 64; ++o) {
        float v = src[(long)o << 14] * scw[oh * 64 + o];
        s += v;
        m = fmaxf(m, v);
    }
    if (oh) { ssum[w] = s; smax[w] = m; }
    __syncthreads();
    if (!oh) {
        s += ssum[w];
        m = fmaxf(m, smax[w]);
        float* d = sp + b * 2 * 17956;
        d[(h + 3) * 134 + (w + 3)] = s * (1.0f / 128.0f);
        d[17956 + (h + 3) * 134 + (w + 3)] = m;
    }
}

// FUSED: 7x7 spatial-attention conv (2->1 ch) + bn + sigmoid, then apply
// out = out*cw*sw + x in the same block.
__global__ __launch_bounds__(256) void sattn_kernel(const float* __restrict__ sp,
        const float* __restrict__ k98, const float* __restrict__ g, const float* __restrict__ bb,
        const float* __restrict__ cw, const float* __restrict__ x, float* __restrict__ out) {
    int b = blockIdx.x >> 7, h = blockIdx.x & 127;
    int tid = threadIdx.x;
    __shared__ float ls[2][7][134];
    __shared__ float lk[98];
    __shared__ float sws[128];
    __shared__ float scw[128];
    const float* sb = sp + b * 2 * 17956;
    for (int idx = tid; idx < 2 * 7 * 134; idx += 256) {
        int c = idx / 938, rr = idx % 938;
        int ky = rr / 134, wp = rr % 134;
        ls[c][ky][wp] = sb[c * 17956 + (h + ky) * 134 + wp];
    }
    if (tid < 98) lk[tid] = k98[tid];
    if (tid >= 128) scw[tid - 128] = cw[(b << 7) + (tid - 128)];
    __syncthreads();
    if (tid < 128) {
        float s = 0.f;
        #pragma unroll
        for (int c = 0; c < 2; ++c)
            #pragma unroll
            for (int ky = 0; ky < 7; ++ky)
                #pragma unroll
                for (int kx = 0; kx < 7; ++kx)
                    s += ls[c][ky][tid + kx] * lk[c * 49 + ky * 7 + kx];
        s = s * (g[0] * rsqrtf(1.0f + 1e-5f)) + bb[0];
        sws[tid] = 1.0f / (1.0f + expf(-s));
    }
    __syncthreads();
    // apply: out[b][o][h][:] = out*scw[o]*sws[:] + x, float4, coalesced rows
    int w4 = tid & 31, og = tid >> 5;
    long base = (((long)b << 21) + (h << 7)) + (w4 << 2);
    float4_t sv = *(const float4_t*)&sws[w4 << 2];
    #pragma unroll
    for (int o = og; o < 128; o += 8) {
        long idx = base + ((long)o << 14);
        float4_t ov = *(const float4_t*)&out[idx];
        float4_t xv = *(const float4_t*)&x[idx];
        float4_t r = ov * scw[o] * sv + xv;
        *(float4_t*)&out[idx] = r;
    }
}

extern "C" void kernel_launch(void* const* d_in, const int* in_sizes, int n_in,
                              void* d_out, int out_size, void* d_ws, size_t ws_size,
                              hipStream_t stream) {
    const float* x       = (const float*)d_in[0];
    const float* experts = (const float*)d_in[1];
    const float* rw1     = (const float*)d_in[2];
    const float* rbn1_g  = (const float*)d_in[3];
    const float* rbn1_b  = (const float*)d_in[4];
    const float* rw2     = (const float*)d_in[5];
    const float* rbn2_g  = (const float*)d_in[6];
    const float* rbn2_b  = (const float*)d_in[7];
    const float* rw3     = (const float*)d_in[8];
    const float* rb3     = (const float*)d_in[9];
    const float* ca_w1   = (const float*)d_in[10];
    const float* ca_bn1g = (const float*)d_in[11];
    const float* ca_bn1b = (const float*)d_in[12];
    const float* ca_w2   = (const float*)d_in[13];
    const float* ca_bn2g = (const float*)d_in[14];
    const float* ca_bn2b = (const float*)d_in[15];
    const float* sa_w    = (const float*)d_in[16];
    const float* sa_g    = (const float*)d_in[17];
    const float* sa_b    = (const float*)d_in[18];
    float* out = (float*)d_out;
    char* ws = (char*)d_ws;

    ushort_t* xn  = (ushort_t*)(ws);
    ushort_t* w2  = (ushort_t*)(ws + 69222400);
    float*    p   = (float*)(ws + 73940992);
    float*    cp  = (float*)(ws + 73949184);
    float*    rwt = (float*)(ws + 73957376);
    float*    cw  = (float*)(ws + 73958400);
    float*    sp  = (float*)(ws + 73966592);

    hipLaunchKernelGGL(init_kernel, dim3(6389), dim3(256), 0, stream, p, cp, sp, xn);
    hipLaunchKernelGGL(transpose_kernel, dim3(4096), dim3(256), 0, stream, x, xn, p);
    hipLaunchKernelGGL(routing_kernel, dim3(1), dim3(256), 0, stream,
                       p, rw1, rbn1_g, rbn1_b, rw2, rbn2_g, rbn2_b, rw3, rb3, rwt);
    hipLaunchKernelGGL(wgen_kernel, dim3(2048), dim3(256), 0, stream, experts, rwt, w2);
    hipLaunchKernelGGL(conv_kernel, dim3(1024), dim3(512), 0, stream, xn, w2, out, cp);
    hipLaunchKernelGGL(se_kernel, dim3(1), dim3(256), 0, stream,
                       cp, ca_w1, ca_bn1g, ca_bn1b, ca_w2, ca_bn2g, ca_bn2b, cw);
    hipLaunchKernelGGL(stat_kernel, dim3(2048), dim3(256), 0, stream, out, cw, sp);
    hipLaunchKernelGGL(sattn_kernel, dim3(2048), dim3(256), 0, stream,
                       sp, sa_w, sa_g, sa_b, cw, x, out);
}

// Round 5
// 482.838 us; speedup vs baseline: 1.0419x; 1.0419x over previous
//
#include <hip/hip_runtime.h>

typedef unsigned short ushort_t;
typedef __attribute__((ext_vector_type(4))) float float4_t;
typedef __attribute__((ext_vector_type(8))) short short8_t;
typedef __attribute__((ext_vector_type(8))) unsigned short ushort8_t;

// fp32 -> bf16 round-to-nearest-even (raw bits)
__device__ __forceinline__ ushort_t f2bf(float f) {
    unsigned u = __builtin_bit_cast(unsigned, f);
    u = (u + 0x7fffu + ((u >> 16) & 1u)) >> 16;
    return (ushort_t)u;
}

// async global->LDS, 16B per lane; lds dest is wave-uniform base (HW adds lane*16)
__device__ __forceinline__ void gld16(const void* g, void* l) {
    __builtin_amdgcn_global_load_lds(
        (const __attribute__((address_space(1))) unsigned int*)g,
        (__attribute__((address_space(3))) unsigned int*)l, 16, 0, 0);
}

// ---------------------------------------------------------------------------
// ws layout (bytes):
//   xn  [16][130][130][128] bf16  @ 0          NHWC + 1px zero halo
//   w2  [16][9][128][128]  bf16   @ 69222400   per-sample weights
//   p   [16][128] f32             @ 73940992   routing avgpool
//   cp  [16][128] f32             @ 73949184   SE channel sums (raw)
//   (unused)                      @ 73957376
//   cw  [16][128] f32             @ 73958400   SE sigmoid weights
//   sp  [16][2][134][134] f32     @ 73966592   spatial stats, 3px zero halo
// ---------------------------------------------------------------------------

__global__ __launch_bounds__(256) void init_kernel(float* __restrict__ p, float* __restrict__ cp,
                                                   float* __restrict__ sp, ushort_t* __restrict__ xn) {
    int t = blockIdx.x * 256 + threadIdx.x;
    if (t < 2048) { p[t] = 0.f; return; }
    if (t < 4096) { cp[t - 2048] = 0.f; return; }
    if (t < 4096 + 574592) { sp[t - 4096] = 0.f; return; }
    int e = t - (4096 + 574592);
    if (e < 1056768) {                 // 16 * 516 * 128 halo elements
        int b = e / 66048;             // 516*128
        int r = e % 66048;
        int pix = r >> 7, i = r & 127;
        int hp, wp;
        if (pix < 130)      { hp = 0;   wp = pix; }
        else if (pix < 260) { hp = 129; wp = pix - 130; }
        else { int q = pix - 260; hp = 1 + (q >> 1); wp = (q & 1) ? 129 : 0; }
        xn[((b * 130 + hp) * 130 + wp) * 128 + i] = 0;
    }
}

// NCHW fp32 -> NHWC bf16 (haloed), fused routing avg-pool partial sums.
__global__ __launch_bounds__(256) void transpose_kernel(const float* __restrict__ x,
                                                        ushort_t* __restrict__ xn,
                                                        float* __restrict__ p) {
    __shared__ float tile[128][65];
    int blk = blockIdx.x;
    int wt = blk & 1, h = (blk >> 1) & 127, b = blk >> 8;
    int w0 = wt * 64;
    int tid = threadIdx.x;
    int wl = tid & 63, ig = tid >> 6;
    const float* src = x + ((long)(b * 128) * 128 + h) * 128 + w0 + wl;  // x[b][i][h][w]
    #pragma unroll
    for (int i = ig; i < 128; i += 4) tile[i][wl] = src[(long)i * 16384];
    __syncthreads();
    if (tid < 128) {   // routing avgpool partials (fp32, pre-quantization)
        float s = 0.f;
        #pragma unroll
        for (int w = 0; w < 64; ++w) s += tile[tid][w];
        atomicAdd(&p[b * 128 + tid], s * (1.0f / 16384.0f));
    }
    int l16 = tid & 15, wq = tid >> 4;
    #pragma unroll
    for (int pass = 0; pass < 4; ++pass) {
        int w = wq + pass * 16;
        ushort8_t v;
        #pragma unroll
        for (int j = 0; j < 8; ++j) v[j] = f2bf(tile[l16 * 8 + j][w]);
        *(ushort8_t*)&xn[((b * 130 + h + 1) * 130 + (w0 + w + 1)) * 128 + l16 * 8] = v;
    }
}

// FUSED routing MLP + expert mix, single pass over experts.
// grid 128 (one block per o). Experts for this o (16e x 128i x 9d = 73728B)
// DMA-staged into LDS ONCE; routing MLP computed redundantly per block (tiny).
// Expert HBM traffic: 151 MB (16x re-read) -> 9.4 MB.
__global__ __launch_bounds__(256) void wgen_kernel(const float* __restrict__ experts,
        const float* __restrict__ p,
        const float* __restrict__ rw1, const float* __restrict__ g1, const float* __restrict__ b1,
        const float* __restrict__ rw2, const float* __restrict__ g2, const float* __restrict__ b2,
        const float* __restrict__ rw3, const float* __restrict__ rb3,
        ushort_t* __restrict__ w2) {
    int o = blockIdx.x;
    int tid = threadIdx.x;
    int lane = tid & 63, wave = tid >> 6;
    __shared__ __align__(16) float ex[16 * 1152];   // [e][i*9+d]
    __shared__ float sg[16][128];
    __shared__ float sh[16][16];
    __shared__ float sl[16][16];
    __shared__ float rwl[16][16];

    // 1) issue expert DMA (4608 B per e = 4.5 wave-segments)
    const float* ebase = experts + (long)o * 1152;
    #pragma unroll
    for (int j = 0; j < 4; ++j) {
        int e = wave * 4 + j;
        const char* src = (const char*)(ebase + (long)e * 147456) + lane * 16;
        char* dst = (char*)&ex[e * 1152];
        #pragma unroll
        for (int k = 0; k < 5; ++k) {
            if (k < 4 || lane < 32)
                gld16(src + k * 1024, dst + k * 1024);
        }
    }

    // 2) routing MLP (redundant per block; independent of ex)
    const float bns = rsqrtf(1.0f + 1e-5f);
    {   int b = tid >> 4, j = tid & 15;
        float s = 0.f;
        for (int i = 0; i < 128; ++i) s += p[b * 128 + i] * rw1[j * 128 + i];
        s = s * (g1[j] * bns) + b1[j];
        sh[b][j] = fmaxf(s, 0.f); }
    __syncthreads();
    for (int c = 0; c < 8; ++c) {
        int idx = tid + c * 256;
        int b = idx >> 7, j = idx & 127;
        float s = 0.f;
        for (int k = 0; k < 16; ++k) s += sh[b][k] * rw2[j * 16 + k];
        s = s * (g2[j] * bns) + b2[j];
        sg[b][j] = 1.0f / (1.0f + expf(-s));
    }
    __syncthreads();
    {   int b = tid >> 4, e = tid & 15;
        float s = rb3[e];
        for (int j = 0; j < 128; ++j) s += sg[b][j] * rw3[e * 128 + j];
        sl[b][e] = s; }
    __syncthreads();
    {   int b = tid >> 4, e = tid & 15;
        float m = -1e30f;
        for (int k = 0; k < 16; ++k) m = fmaxf(m, sl[b][k]);
        float num = expf(sl[b][e] - m), den = 0.f;
        for (int k = 0; k < 16; ++k) den += expf(sl[b][k] - m);
        rwl[b][e] = num / den; }
    asm volatile("s_waitcnt vmcnt(0)" ::: "memory");
    __syncthreads();

    // 3) mix: w2[b][d][o][i] = sum_e rwl[b][e] * ex[e][i*9+d]; each half does 8 b's
    int i = tid & 127, half = tid >> 7;
    float acc[8][9];
    #pragma unroll
    for (int b = 0; b < 8; ++b)
        #pragma unroll
        for (int d = 0; d < 9; ++d) acc[b][d] = 0.f;
    for (int e = 0; e < 16; ++e) {
        float v[9];
        #pragma unroll
        for (int d = 0; d < 9; ++d) v[d] = ex[e * 1152 + i * 9 + d];
        #pragma unroll
        for (int b = 0; b < 8; ++b) {
            float r = rwl[half * 8 + b][e];
            #pragma unroll
            for (int d = 0; d < 9; ++d) acc[b][d] += v[d] * r;
        }
    }
    #pragma unroll
    for (int b = 0; b < 8; ++b)
        #pragma unroll
        for (int d = 0; d < 9; ++d)
            w2[(((half * 8 + b) * 9 + d) << 14) + (o << 7) + i] = f2bf(acc[b][d]);
}

// Per-sample conv as MFMA implicit GEMM (round-3 proven structure).
// A staged via global_load_lds DMA, quad-buffered, prefetch distance 3;
// register double-buffered fragments (ds_reads for c+1 under c's MFMAs);
// counted vmcnt per chunk, full drains only at the 2 dy boundaries.
// LDS = X 33280B + A 4*8192B = 66048B -> 2 blocks/CU (inter-block overlap).
struct __align__(16) ConvSmem {
    union {
        struct { ushort_t X[16640]; ushort_t A[4][4096]; } t;
        float c[4224];   // epilogue staging: 32 rows x 132 (padded) fp32
    };
};

__global__ __launch_bounds__(256, 2) void conv_kernel(const ushort_t* __restrict__ xn,
                                                      const ushort_t* __restrict__ w2,
                                                      float* __restrict__ out,
                                                      float* __restrict__ cp) {
    __shared__ ConvSmem sm;
    // XCD-aware swizzle (2048 % 8 == 0 -> bijective)
    int bh = (blockIdx.x & 7) * 256 + (blockIdx.x >> 3);
    int b = bh >> 7, h = bh & 127;
    int tid = threadIdx.x;
    int lane = tid & 63, wave = tid >> 6;
    int wm = wave & 1, wn = wave >> 1;
    int q = lane >> 4, nl = lane & 15;

    float4_t acc[4][4];
    #pragma unroll
    for (int mi = 0; mi < 4; ++mi)
        #pragma unroll
        for (int ni = 0; ni < 4; ++ni) acc[mi][ni] = (float4_t){0.f, 0.f, 0.f, 0.f};

    const ushort_t* xbase = xn + (b * 130 + h) * 16640;
    const ushort_t* abase = w2 + (long)b * 147456;

    auto stageX = [&](int dy) {
        const ushort_t* xrow = xbase + dy * 16640;
        #pragma unroll
        for (int seg = wave; seg < 33; seg += 4) {
            if (seg < 32 || lane < 32) {
                int lofs = seg * 512 + lane * 8;
                int pp = lofs >> 7;
                int jb = (lofs & 127) >> 3;
                gld16(xrow + (pp << 7) + ((jb ^ (pp & 15)) << 3), &sm.t.X[seg * 512]);
            }
        }
    };
    auto stageA = [&](int c) {   // c = chunk 0..35; exactly 2 gld16 per wave
        int dy = c / 12, rem = c % 12, dx = rem >> 2, ic = rem & 3;
        const ushort_t* ab = abase + (dy * 3 + dx) * 16384 + ic * 32;
        int buf = c & 3;
        int ol = lane >> 2;
        int jsrc = (lane & 3) ^ ((ol >> 1) & 3);   // bank-spread swizzle: f(o) = (o>>1)&3
        #pragma unroll
        for (int inst = 0; inst < 2; ++inst) {
            int ob = wave * 32 + inst * 16;
            gld16(ab + (ob + ol) * 128 + (jsrc << 3), &sm.t.A[buf][ob * 32]);
        }
    };

    short8_t afr[2][4], bfr[2][4];
    auto readFrag = [&](int cc) {            // parity pb = cc & 1
        int pb = cc & 1;
        int dx = (cc % 12) >> 2, ic = cc & 3;
        const ushort_t* ap = &sm.t.A[cc & 3][0];
        #pragma unroll
        for (int mi = 0; mi < 4; ++mi) {
            int o = wm * 64 + mi * 16 + nl;
            afr[pb][mi] = *(const short8_t*)&ap[(o << 5) + ((q ^ ((o >> 1) & 3)) << 3)];
        }
        #pragma unroll
        for (int ni = 0; ni < 4; ++ni) {
            int pp = wn * 64 + ni * 16 + nl + dx;
            int J = ic * 4 + q;
            bfr[pb][ni] = *(const short8_t*)&sm.t.X[(pp << 7) + ((J ^ (pp & 15)) << 3)];
        }
    };
    auto domfma = [&](int pb) {
        __builtin_amdgcn_s_setprio(1);
        #pragma unroll
        for (int mi = 0; mi < 4; ++mi)
            #pragma unroll
            for (int ni = 0; ni < 4; ++ni)
                acc[mi][ni] = __builtin_amdgcn_mfma_f32_16x16x32_bf16(
                    afr[pb][mi], bfr[pb][ni], acc[mi][ni], 0, 0, 0);
        __builtin_amdgcn_s_setprio(0);
    };

    // prologue: X row 0 + A chunks 0..2, one full drain
    stageX(0);
    stageA(0); stageA(1); stageA(2);
    asm volatile("s_waitcnt vmcnt(0)" ::: "memory");
    __builtin_amdgcn_s_barrier();
    readFrag(0);

    #pragma unroll
    for (int c = 0; c < 36; ++c) {
        if (c + 3 < 36) stageA(c + 3);
        const bool bnd = (c == 11 || c == 23);
        if (!bnd && c + 1 < 36) readFrag(c + 1);   // overlaps with MFMAs below
        domfma(c & 1);
        if (bnd) {
            // dy boundary: restage X, full drain (stageX counts are uneven)
            __builtin_amdgcn_s_barrier();
            stageX(c == 11 ? 1 : 2);
            asm volatile("s_waitcnt vmcnt(0)" ::: "memory");
            __builtin_amdgcn_s_barrier();
            readFrag(c + 1);
        } else if (c < 35) {
            // guarantee A(c+2) complete (read as frag at next chunk's start)
            if (c == 33)
                asm volatile("s_waitcnt vmcnt(0)" ::: "memory");
            else if (!(c == 0 || c == 12 || c == 24 || c == 34))
                asm volatile("s_waitcnt vmcnt(2)" ::: "memory");
            __builtin_amdgcn_s_barrier();
        }
    }

    // SE channel sums (shuffle-reduce + one atomic per o)
    #pragma unroll
    for (int mi = 0; mi < 4; ++mi) {
        int o0 = wm * 64 + mi * 16 + q * 4;
        float rs[4] = {0.f, 0.f, 0.f, 0.f};
        #pragma unroll
        for (int ni = 0; ni < 4; ++ni) {
            float4_t v = acc[mi][ni];
            #pragma unroll
            for (int r = 0; r < 4; ++r) rs[r] += v[r];
        }
        #pragma unroll
        for (int r = 0; r < 4; ++r) {
            for (int msk = 1; msk < 16; msk <<= 1) rs[r] += __shfl_xor(rs[r], msk, 64);
            if (nl == 0) atomicAdd(&cp[(b << 7) + o0 + r], rs[r]);
        }
    }

    // C store via LDS slices -> full 128B-line coalesced writes
    float* outb = out + (((long)(b << 7)) << 14) + (h << 7);
    #pragma unroll
    for (int os = 0; os < 4; ++os) {
        __syncthreads();   // previous slice readers / K-loop LDS readers done
        if (wm == (os >> 1)) {
            #pragma unroll
            for (int mi2 = 0; mi2 < 2; ++mi2) {
                int mi = (os & 1) * 2 + mi2;
                #pragma unroll
                for (int ni = 0; ni < 4; ++ni) {
                    float4_t v = acc[mi][ni];
                    int orow = mi2 * 16 + q * 4;
                    int w = wn * 64 + ni * 16 + nl;
                    #pragma unroll
                    for (int rr = 0; rr < 4; ++rr) sm.c[(orow + rr) * 132 + w] = v[rr];
                }
            }
        }
        __syncthreads();
        int row = tid >> 3, j8 = tid & 7;
        float* og = outb + ((long)(os * 32 + row) << 14);
        #pragma unroll
        for (int k = 0; k < 4; ++k) {
            float4_t v = *(const float4_t*)&sm.c[row * 132 + j8 * 4 + k * 32];
            *(float4_t*)&og[j8 * 4 + k * 32] = v;
        }
    }
}

// FUSED SE + spatial stats: each block computes cw[b][:] from cp (tiny MLP,
// redundant), uses it for the channel-weighted mean/max; h==0 blocks publish
// cw to global for sattn. Removes the serialized 1-block se_kernel launch.
__global__ __launch_bounds__(256) void stat_kernel(const float* __restrict__ out,
        const float* __restrict__ cp,
        const float* __restrict__ w1, const float* __restrict__ g1, const float* __restrict__ b1,
        const float* __restrict__ w2, const float* __restrict__ g2, const float* __restrict__ b2,
        float* __restrict__ cw, float* __restrict__ sp) {
    int b = blockIdx.x >> 7, h = blockIdx.x & 127;
    int tid = threadIdx.x;
    __shared__ float scp[128], sch[16], scw[128], ssum[128], smax[128];
    const float bns = rsqrtf(1.0f + 1e-5f);
    if (tid < 128) scp[tid] = cp[(b << 7) + tid] * (1.0f / 16384.0f);
    __syncthreads();
    if (tid < 16) {
        float s = 0.f;
        for (int o = 0; o < 128; ++o) s += scp[o] * w1[tid * 128 + o];
        s = s * (g1[tid] * bns) + b1[tid];
        sch[tid] = fmaxf(s, 0.f);
    }
    __syncthreads();
    if (tid < 128) {
        float s = 0.f;
        #pragma unroll
        for (int k = 0; k < 16; ++k) s += sch[k] * w2[tid * 16 + k];
        s = s * (g2[tid] * bns) + b2[tid];
        scw[tid] = 1.0f / (1.0f + expf(-s));
        if (h == 0) cw[(b << 7) + tid] = scw[tid];
    }
    __syncthreads();
    int w = tid & 127, oh = tid >> 7;
    const float* src = out + ((long)b << 21) + ((long)(oh * 64) << 14) + (h << 7) + w;
    float s = 0.f, m = -1e30f;
    #pragma unroll 8
    for (int o = 0; o < 64; ++o) {
        float v = src[(long)o << 14] * scw[oh * 64 + o];
        s += v;
        m = fmaxf(m, v);
    }
    if (oh) { ssum[w] = s; smax[w] = m; }
    __syncthreads();
    if (!oh) {
        s += ssum[w];
        m = fmaxf(m, smax[w]);
        float* d = sp + b * 2 * 17956;
        d[(h + 3) * 134 + (w + 3)] = s * (1.0f / 128.0f);
        d[17956 + (h + 3) * 134 + (w + 3)] = m;
    }
}

// FUSED: 7x7 spatial-attention conv (2->1 ch) + bn + sigmoid, then apply
// out = out*cw*sw + x in the same block.
__global__ __launch_bounds__(256) void sattn_kernel(const float* __restrict__ sp,
        const float* __restrict__ k98, const float* __restrict__ g, const float* __restrict__ bb,
        const float* __restrict__ cw, const float* __restrict__ x, float* __restrict__ out) {
    int b = blockIdx.x >> 7, h = blockIdx.x & 127;
    int tid = threadIdx.x;
    __shared__ float ls[2][7][134];
    __shared__ float lk[98];
    __shared__ float sws[128];
    __shared__ float scw[128];
    const float* sb = sp + b * 2 * 17956;
    for (int idx = tid; idx < 2 * 7 * 134; idx += 256) {
        int c = idx / 938, rr = idx % 938;
        int ky = rr / 134, wp = rr % 134;
        ls[c][ky][wp] = sb[c * 17956 + (h + ky) * 134 + wp];
    }
    if (tid < 98) lk[tid] = k98[tid];
    if (tid >= 128) scw[tid - 128] = cw[(b << 7) + (tid - 128)];
    __syncthreads();
    if (tid < 128) {
        float s = 0.f;
        #pragma unroll
        for (int c = 0; c < 2; ++c)
            #pragma unroll
            for (int ky = 0; ky < 7; ++ky)
                #pragma unroll
                for (int kx = 0; kx < 7; ++kx)
                    s += ls[c][ky][tid + kx] * lk[c * 49 + ky * 7 + kx];
        s = s * (g[0] * rsqrtf(1.0f + 1e-5f)) + bb[0];
        sws[tid] = 1.0f / (1.0f + expf(-s));
    }
    __syncthreads();
    // apply: out[b][o][h][:] = out*scw[o]*sws[:] + x, float4, coalesced rows
    int w4 = tid & 31, og = tid >> 5;
    long base = (((long)b << 21) + (h << 7)) + (w4 << 2);
    float4_t sv = *(const float4_t*)&sws[w4 << 2];
    #pragma unroll
    for (int o = og; o < 128; o += 8) {
        long idx = base + ((long)o << 14);
        float4_t ov = *(const float4_t*)&out[idx];
        float4_t xv = *(const float4_t*)&x[idx];
        float4_t r = ov * scw[o] * sv + xv;
        *(float4_t*)&out[idx] = r;
    }
}

extern "C" void kernel_launch(void* const* d_in, const int* in_sizes, int n_in,
                              void* d_out, int out_size, void* d_ws, size_t ws_size,
                              hipStream_t stream) {
    const float* x       = (const float*)d_in[0];
    const float* experts = (const float*)d_in[1];
    const float* rw1     = (const float*)d_in[2];
    const float* rbn1_g  = (const float*)d_in[3];
    const float* rbn1_b  = (const float*)d_in[4];
    const float* rw2     = (const float*)d_in[5];
    const float* rbn2_g  = (const float*)d_in[6];
    const float* rbn2_b  = (const float*)d_in[7];
    const float* rw3     = (const float*)d_in[8];
    const float* rb3     = (const float*)d_in[9];
    const float* ca_w1   = (const float*)d_in[10];
    const float* ca_bn1g = (const float*)d_in[11];
    const float* ca_bn1b = (const float*)d_in[12];
    const float* ca_w2   = (const float*)d_in[13];
    const float* ca_bn2g = (const float*)d_in[14];
    const float* ca_bn2b = (const float*)d_in[15];
    const float* sa_w    = (const float*)d_in[16];
    const float* sa_g    = (const float*)d_in[17];
    const float* sa_b    = (const float*)d_in[18];
    float* out = (float*)d_out;
    char* ws = (char*)d_ws;

    ushort_t* xn  = (ushort_t*)(ws);
    ushort_t* w2  = (ushort_t*)(ws + 69222400);
    float*    p   = (float*)(ws + 73940992);
    float*    cp  = (float*)(ws + 73949184);
    float*    cw  = (float*)(ws + 73958400);
    float*    sp  = (float*)(ws + 73966592);

    hipLaunchKernelGGL(init_kernel, dim3(6389), dim3(256), 0, stream, p, cp, sp, xn);
    hipLaunchKernelGGL(transpose_kernel, dim3(4096), dim3(256), 0, stream, x, xn, p);
    hipLaunchKernelGGL(wgen_kernel, dim3(128), dim3(256), 0, stream,
                       experts, p, rw1, rbn1_g, rbn1_b, rw2, rbn2_g, rbn2_b, rw3, rb3, w2);
    hipLaunchKernelGGL(conv_kernel, dim3(2048), dim3(256), 0, stream, xn, w2, out, cp);
    hipLaunchKernelGGL(stat_kernel, dim3(2048), dim3(256), 0, stream,
                       out, cp, ca_w1, ca_bn1g, ca_bn1b, ca_w2, ca_bn2g, ca_bn2b, cw, sp);
    hipLaunchKernelGGL(sattn_kernel, dim3(2048), dim3(256), 0, stream,
                       sp, sa_w, sa_g, sa_b, cw, x, out);
}

// Round 6
// 465.119 us; speedup vs baseline: 1.0816x; 1.0381x over previous
//
#include <hip/hip_runtime.h>

typedef unsigned short ushort_t;
typedef __attribute__((ext_vector_type(4))) float float4_t;
typedef __attribute__((ext_vector_type(8))) short short8_t;
typedef __attribute__((ext_vector_type(8))) unsigned short ushort8_t;
typedef __attribute__((ext_vector_type(4))) unsigned short ushort4_t;

// fp32 -> bf16 round-to-nearest-even (raw bits)
__device__ __forceinline__ ushort_t f2bf(float f) {
    unsigned u = __builtin_bit_cast(unsigned, f);
    u = (u + 0x7fffu + ((u >> 16) & 1u)) >> 16;
    return (ushort_t)u;
}
// fp32 <-> fp16 (RTNE via v_cvt)
__device__ __forceinline__ ushort_t f2h(float f) {
    return __builtin_bit_cast(unsigned short, (_Float16)f);
}
__device__ __forceinline__ float h2f(ushort_t u) {
    return (float)__builtin_bit_cast(_Float16, u);
}

// async global->LDS, 16B per lane; lds dest is wave-uniform base (HW adds lane*16)
__device__ __forceinline__ void gld16(const void* g, void* l) {
    __builtin_amdgcn_global_load_lds(
        (const __attribute__((address_space(1))) unsigned int*)g,
        (__attribute__((address_space(3))) unsigned int*)l, 16, 0, 0);
}

// ---------------------------------------------------------------------------
// ws layout (bytes):
//   xn   [16][130][130][128] bf16  @ 0          NHWC + 1px zero halo
//   w2   [16][9][128][128]  bf16   @ 69222400   per-sample weights
//   p    [16][128] f32             @ 73940992   routing avgpool
//   cp   [16][128] f32             @ 73949184   SE channel sums (raw)
//   cw   [16][128] f32             @ 73958400   SE sigmoid weights
//   sp   [16][2][134][134] f32     @ 73966592   spatial stats, 3px zero halo
//   outi [16][128][128][128] fp16  @ 76264960   conv result (intermediate)
//   total 143373824 B (~143.4 MB)
// ---------------------------------------------------------------------------

__global__ __launch_bounds__(256) void init_kernel(float* __restrict__ p, float* __restrict__ cp,
                                                   float* __restrict__ sp, ushort_t* __restrict__ xn) {
    int t = blockIdx.x * 256 + threadIdx.x;
    if (t < 2048) { p[t] = 0.f; return; }
    if (t < 4096) { cp[t - 2048] = 0.f; return; }
    if (t < 4096 + 574592) { sp[t - 4096] = 0.f; return; }
    int e = t - (4096 + 574592);
    if (e < 1056768) {                 // 16 * 516 * 128 halo elements
        int b = e / 66048;             // 516*128
        int r = e % 66048;
        int pix = r >> 7, i = r & 127;
        int hp, wp;
        if (pix < 130)      { hp = 0;   wp = pix; }
        else if (pix < 260) { hp = 129; wp = pix - 130; }
        else { int q = pix - 260; hp = 1 + (q >> 1); wp = (q & 1) ? 129 : 0; }
        xn[((b * 130 + hp) * 130 + wp) * 128 + i] = 0;
    }
}

// NCHW fp32 -> NHWC bf16 (haloed), fused routing avg-pool partial sums.
__global__ __launch_bounds__(256) void transpose_kernel(const float* __restrict__ x,
                                                        ushort_t* __restrict__ xn,
                                                        float* __restrict__ p) {
    __shared__ float tile[128][65];
    int blk = blockIdx.x;
    int wt = blk & 1, h = (blk >> 1) & 127, b = blk >> 8;
    int w0 = wt * 64;
    int tid = threadIdx.x;
    int wl = tid & 63, ig = tid >> 6;
    const float* src = x + ((long)(b * 128) * 128 + h) * 128 + w0 + wl;  // x[b][i][h][w]
    #pragma unroll
    for (int i = ig; i < 128; i += 4) tile[i][wl] = src[(long)i * 16384];
    __syncthreads();
    if (tid < 128) {   // routing avgpool partials (fp32, pre-quantization)
        float s = 0.f;
        #pragma unroll
        for (int w = 0; w < 64; ++w) s += tile[tid][w];
        atomicAdd(&p[b * 128 + tid], s * (1.0f / 16384.0f));
    }
    int l16 = tid & 15, wq = tid >> 4;
    #pragma unroll
    for (int pass = 0; pass < 4; ++pass) {
        int w = wq + pass * 16;
        ushort8_t v;
        #pragma unroll
        for (int j = 0; j < 8; ++j) v[j] = f2bf(tile[l16 * 8 + j][w]);
        *(ushort8_t*)&xn[((b * 130 + h + 1) * 130 + (w0 + w + 1)) * 128 + l16 * 8] = v;
    }
}

// FUSED routing MLP + expert mix, single pass over experts.
// grid 128 (one block per o). Experts for this o (16e x 128i x 9d = 73728B)
// DMA-staged into LDS ONCE; routing MLP computed redundantly per block (tiny).
__global__ __launch_bounds__(256) void wgen_kernel(const float* __restrict__ experts,
        const float* __restrict__ p,
        const float* __restrict__ rw1, const float* __restrict__ g1, const float* __restrict__ b1,
        const float* __restrict__ rw2, const float* __restrict__ g2, const float* __restrict__ b2,
        const float* __restrict__ rw3, const float* __restrict__ rb3,
        ushort_t* __restrict__ w2) {
    int o = blockIdx.x;
    int tid = threadIdx.x;
    int lane = tid & 63, wave = tid >> 6;
    __shared__ __align__(16) float ex[16 * 1152];   // [e][i*9+d]
    __shared__ float sg[16][128];
    __shared__ float sh[16][16];
    __shared__ float sl[16][16];
    __shared__ float rwl[16][16];

    // 1) issue expert DMA (4608 B per e = 4.5 wave-segments)
    const float* ebase = experts + (long)o * 1152;
    #pragma unroll
    for (int j = 0; j < 4; ++j) {
        int e = wave * 4 + j;
        const char* src = (const char*)(ebase + (long)e * 147456) + lane * 16;
        char* dst = (char*)&ex[e * 1152];
        #pragma unroll
        for (int k = 0; k < 5; ++k) {
            if (k < 4 || lane < 32)
                gld16(src + k * 1024, dst + k * 1024);
        }
    }

    // 2) routing MLP (redundant per block; independent of ex)
    const float bns = rsqrtf(1.0f + 1e-5f);
    {   int b = tid >> 4, j = tid & 15;
        float s = 0.f;
        for (int i = 0; i < 128; ++i) s += p[b * 128 + i] * rw1[j * 128 + i];
        s = s * (g1[j] * bns) + b1[j];
        sh[b][j] = fmaxf(s, 0.f); }
    __syncthreads();
    for (int c = 0; c < 8; ++c) {
        int idx = tid + c * 256;
        int b = idx >> 7, j = idx & 127;
        float s = 0.f;
        for (int k = 0; k < 16; ++k) s += sh[b][k] * rw2[j * 16 + k];
        s = s * (g2[j] * bns) + b2[j];
        sg[b][j] = 1.0f / (1.0f + expf(-s));
    }
    __syncthreads();
    {   int b = tid >> 4, e = tid & 15;
        float s = rb3[e];
        for (int j = 0; j < 128; ++j) s += sg[b][j] * rw3[e * 128 + j];
        sl[b][e] = s; }
    __syncthreads();
    {   int b = tid >> 4, e = tid & 15;
        float m = -1e30f;
        for (int k = 0; k < 16; ++k) m = fmaxf(m, sl[b][k]);
        float num = expf(sl[b][e] - m), den = 0.f;
        for (int k = 0; k < 16; ++k) den += expf(sl[b][k] - m);
        rwl[b][e] = num / den; }
    asm volatile("s_waitcnt vmcnt(0)" ::: "memory");
    __syncthreads();

    // 3) mix: w2[b][d][o][i] = sum_e rwl[b][e] * ex[e][i*9+d]; each half does 8 b's
    int i = tid & 127, half = tid >> 7;
    float acc[8][9];
    #pragma unroll
    for (int b = 0; b < 8; ++b)
        #pragma unroll
        for (int d = 0; d < 9; ++d) acc[b][d] = 0.f;
    for (int e = 0; e < 16; ++e) {
        float v[9];
        #pragma unroll
        for (int d = 0; d < 9; ++d) v[d] = ex[e * 1152 + i * 9 + d];
        #pragma unroll
        for (int b = 0; b < 8; ++b) {
            float r = rwl[half * 8 + b][e];
            #pragma unroll
            for (int d = 0; d < 9; ++d) acc[b][d] += v[d] * r;
        }
    }
    #pragma unroll
    for (int b = 0; b < 8; ++b)
        #pragma unroll
        for (int d = 0; d < 9; ++d)
            w2[(((half * 8 + b) * 9 + d) << 14) + (o << 7) + i] = f2bf(acc[b][d]);
}

// Per-sample conv as MFMA implicit GEMM (round-3 proven structure).
// A staged via global_load_lds DMA, quad-buffered, prefetch distance 3;
// register double-buffered fragments; counted vmcnt per chunk, full drains
// only at the 2 dy boundaries. Output written as fp16 (halves WRITE traffic;
// intermediate only -- final residual applied in fp32 by sattn).
// LDS = X 33280B + A 4*8192B = 66048B -> 2 blocks/CU (inter-block overlap).
struct __align__(16) ConvSmem {
    union {
        struct { ushort_t X[16640]; ushort_t A[4][4096]; } t;
        float c[4224];   // epilogue staging: 32 rows x 132 (padded) fp32
    };
};

__global__ __launch_bounds__(256, 2) void conv_kernel(const ushort_t* __restrict__ xn,
                                                      const ushort_t* __restrict__ w2,
                                                      ushort_t* __restrict__ outi,
                                                      float* __restrict__ cp) {
    __shared__ ConvSmem sm;
    // XCD-aware swizzle (2048 % 8 == 0 -> bijective)
    int bh = (blockIdx.x & 7) * 256 + (blockIdx.x >> 3);
    int b = bh >> 7, h = bh & 127;
    int tid = threadIdx.x;
    int lane = tid & 63, wave = tid >> 6;
    int wm = wave & 1, wn = wave >> 1;
    int q = lane >> 4, nl = lane & 15;

    float4_t acc[4][4];
    #pragma unroll
    for (int mi = 0; mi < 4; ++mi)
        #pragma unroll
        for (int ni = 0; ni < 4; ++ni) acc[mi][ni] = (float4_t){0.f, 0.f, 0.f, 0.f};

    const ushort_t* xbase = xn + (b * 130 + h) * 16640;
    const ushort_t* abase = w2 + (long)b * 147456;

    auto stageX = [&](int dy) {
        const ushort_t* xrow = xbase + dy * 16640;
        #pragma unroll
        for (int seg = wave; seg < 33; seg += 4) {
            if (seg < 32 || lane < 32) {
                int lofs = seg * 512 + lane * 8;
                int pp = lofs >> 7;
                int jb = (lofs & 127) >> 3;
                gld16(xrow + (pp << 7) + ((jb ^ (pp & 15)) << 3), &sm.t.X[seg * 512]);
            }
        }
    };
    auto stageA = [&](int c) {   // c = chunk 0..35; exactly 2 gld16 per wave
        int dy = c / 12, rem = c % 12, dx = rem >> 2, ic = rem & 3;
        const ushort_t* ab = abase + (dy * 3 + dx) * 16384 + ic * 32;
        int buf = c & 3;
        int ol = lane >> 2;
        int jsrc = (lane & 3) ^ ((ol >> 1) & 3);   // bank-spread swizzle: f(o) = (o>>1)&3
        #pragma unroll
        for (int inst = 0; inst < 2; ++inst) {
            int ob = wave * 32 + inst * 16;
            gld16(ab + (ob + ol) * 128 + (jsrc << 3), &sm.t.A[buf][ob * 32]);
        }
    };

    short8_t afr[2][4], bfr[2][4];
    auto readFrag = [&](int cc) {            // parity pb = cc & 1
        int pb = cc & 1;
        int dx = (cc % 12) >> 2, ic = cc & 3;
        const ushort_t* ap = &sm.t.A[cc & 3][0];
        #pragma unroll
        for (int mi = 0; mi < 4; ++mi) {
            int o = wm * 64 + mi * 16 + nl;
            afr[pb][mi] = *(const short8_t*)&ap[(o << 5) + ((q ^ ((o >> 1) & 3)) << 3)];
        }
        #pragma unroll
        for (int ni = 0; ni < 4; ++ni) {
            int pp = wn * 64 + ni * 16 + nl + dx;
            int J = ic * 4 + q;
            bfr[pb][ni] = *(const short8_t*)&sm.t.X[(pp << 7) + ((J ^ (pp & 15)) << 3)];
        }
    };
    auto domfma = [&](int pb) {
        __builtin_amdgcn_s_setprio(1);
        #pragma unroll
        for (int mi = 0; mi < 4; ++mi)
            #pragma unroll
            for (int ni = 0; ni < 4; ++ni)
                acc[mi][ni] = __builtin_amdgcn_mfma_f32_16x16x32_bf16(
                    afr[pb][mi], bfr[pb][ni], acc[mi][ni], 0, 0, 0);
        __builtin_amdgcn_s_setprio(0);
    };

    // prologue: X row 0 + A chunks 0..2, one full drain
    stageX(0);
    stageA(0); stageA(1); stageA(2);
    asm volatile("s_waitcnt vmcnt(0)" ::: "memory");
    __builtin_amdgcn_s_barrier();
    readFrag(0);

    #pragma unroll
    for (int c = 0; c < 36; ++c) {
        if (c + 3 < 36) stageA(c + 3);
        const bool bnd = (c == 11 || c == 23);
        if (!bnd && c + 1 < 36) readFrag(c + 1);   // overlaps with MFMAs below
        domfma(c & 1);
        if (bnd) {
            // dy boundary: restage X, full drain (stageX counts are uneven)
            __builtin_amdgcn_s_barrier();
            stageX(c == 11 ? 1 : 2);
            asm volatile("s_waitcnt vmcnt(0)" ::: "memory");
            __builtin_amdgcn_s_barrier();
            readFrag(c + 1);
        } else if (c < 35) {
            // guarantee A(c+2) complete (read as frag at next chunk's start)
            if (c == 33)
                asm volatile("s_waitcnt vmcnt(0)" ::: "memory");
            else if (!(c == 0 || c == 12 || c == 24 || c == 34))
                asm volatile("s_waitcnt vmcnt(2)" ::: "memory");
            __builtin_amdgcn_s_barrier();
        }
    }

    // SE channel sums (shuffle-reduce + one atomic per o) -- fp32 accumulators
    #pragma unroll
    for (int mi = 0; mi < 4; ++mi) {
        int o0 = wm * 64 + mi * 16 + q * 4;
        float rs[4] = {0.f, 0.f, 0.f, 0.f};
        #pragma unroll
        for (int ni = 0; ni < 4; ++ni) {
            float4_t v = acc[mi][ni];
            #pragma unroll
            for (int r = 0; r < 4; ++r) rs[r] += v[r];
        }
        #pragma unroll
        for (int r = 0; r < 4; ++r) {
            for (int msk = 1; msk < 16; msk <<= 1) rs[r] += __shfl_xor(rs[r], msk, 64);
            if (nl == 0) atomicAdd(&cp[(b << 7) + o0 + r], rs[r]);
        }
    }

    // C store via LDS slices -> coalesced fp16 row writes (256B per o-row)
    ushort_t* outb = outi + (((long)(b << 7)) << 14) + (h << 7);
    #pragma unroll
    for (int os = 0; os < 4; ++os) {
        __syncthreads();   // previous slice readers / K-loop LDS readers done
        if (wm == (os >> 1)) {
            #pragma unroll
            for (int mi2 = 0; mi2 < 2; ++mi2) {
                int mi = (os & 1) * 2 + mi2;
                #pragma unroll
                for (int ni = 0; ni < 4; ++ni) {
                    float4_t v = acc[mi][ni];
                    int orow = mi2 * 16 + q * 4;
                    int w = wn * 64 + ni * 16 + nl;
                    #pragma unroll
                    for (int rr = 0; rr < 4; ++rr) sm.c[(orow + rr) * 132 + w] = v[rr];
                }
            }
        }
        __syncthreads();
        int row = tid >> 4, j = tid & 15;
        #pragma unroll
        for (int pass = 0; pass < 2; ++pass) {
            int r2 = pass * 16 + row;
            ushort8_t v;
            #pragma unroll
            for (int k = 0; k < 8; ++k) v[k] = f2h(sm.c[r2 * 132 + j * 8 + k]);
            *(ushort8_t*)&outb[((long)(os * 32 + r2) << 14) + j * 8] = v;
        }
    }
}

// FUSED SE + spatial stats (fp16 input): each block computes cw[b][:] from cp
// (tiny MLP, redundant), channel-weighted mean/max over o; h==0 publishes cw.
__global__ __launch_bounds__(256) void stat_kernel(const ushort_t* __restrict__ outi,
        const float* __restrict__ cp,
        const float* __restrict__ w1, const float* __restrict__ g1, const float* __restrict__ b1,
        const float* __restrict__ w2, const float* __restrict__ g2, const float* __restrict__ b2,
        float* __restrict__ cw, float* __restrict__ sp) {
    int b = blockIdx.x >> 7, h = blockIdx.x & 127;
    int tid = threadIdx.x;
    __shared__ float scp[128], sch[16], scw[128];
    __shared__ float ssum[4][128], smax[4][128];
    const float bns = rsqrtf(1.0f + 1e-5f);
    if (tid < 128) scp[tid] = cp[(b << 7) + tid] * (1.0f / 16384.0f);
    __syncthreads();
    if (tid < 16) {
        float s = 0.f;
        for (int o = 0; o < 128; ++o) s += scp[o] * w1[tid * 128 + o];
        s = s * (g1[tid] * bns) + b1[tid];
        sch[tid] = fmaxf(s, 0.f);
    }
    __syncthreads();
    if (tid < 128) {
        float s = 0.f;
        #pragma unroll
        for (int k = 0; k < 16; ++k) s += sch[k] * w2[tid * 16 + k];
        s = s * (g2[tid] * bns) + b2[tid];
        scw[tid] = 1.0f / (1.0f + expf(-s));
        if (h == 0) cw[(b << 7) + tid] = scw[tid];
    }
    __syncthreads();
    // channel-weighted mean/max: 4 o-groups of 32, ushort2 per lane (2 w's)
    int wp = (tid & 63) << 1, og = tid >> 6;
    const ushort_t* src = outi + ((long)b << 21) + ((long)(og << 5) << 14) + (h << 7) + wp;
    float s0 = 0.f, s1 = 0.f, m0 = -1e30f, m1 = -1e30f;
    #pragma unroll 8
    for (int o = 0; o < 32; ++o) {
        unsigned u = *(const unsigned*)&src[(long)o << 14];
        float c = scw[(og << 5) + o];
        float v0 = h2f((ushort_t)(u & 0xffffu)) * c;
        float v1 = h2f((ushort_t)(u >> 16)) * c;
        s0 += v0; s1 += v1;
        m0 = fmaxf(m0, v0); m1 = fmaxf(m1, v1);
    }
    ssum[og][wp] = s0; ssum[og][wp + 1] = s1;
    smax[og][wp] = m0; smax[og][wp + 1] = m1;
    __syncthreads();
    if (tid < 128) {
        float s = ssum[0][tid] + ssum[1][tid] + ssum[2][tid] + ssum[3][tid];
        float m = fmaxf(fmaxf(smax[0][tid], smax[1][tid]),
                        fmaxf(smax[2][tid], smax[3][tid]));
        float* d = sp + b * 2 * 17956;
        d[(h + 3) * 134 + (tid + 3)] = s * (1.0f / 128.0f);
        d[17956 + (h + 3) * 134 + (tid + 3)] = m;
    }
}

// FUSED: 7x7 spatial-attention conv (2->1 ch) + bn + sigmoid, then apply
// out = fp16(conv)*cw*sw + x in fp32. Only writer of d_out.
__global__ __launch_bounds__(256) void sattn_kernel(const float* __restrict__ sp,
        const float* __restrict__ k98, const float* __restrict__ g, const float* __restrict__ bb,
        const float* __restrict__ cw, const float* __restrict__ x,
        const ushort_t* __restrict__ outi, float* __restrict__ out) {
    int b = blockIdx.x >> 7, h = blockIdx.x & 127;
    int tid = threadIdx.x;
    __shared__ float ls[2][7][134];
    __shared__ float lk[98];
    __shared__ float sws[128];
    __shared__ float scw[128];
    const float* sb = sp + b * 2 * 17956;
    for (int idx = tid; idx < 2 * 7 * 134; idx += 256) {
        int c = idx / 938, rr = idx % 938;
        int ky = rr / 134, wp = rr % 134;
        ls[c][ky][wp] = sb[c * 17956 + (h + ky) * 134 + wp];
    }
    if (tid < 98) lk[tid] = k98[tid];
    if (tid >= 128) scw[tid - 128] = cw[(b << 7) + (tid - 128)];
    __syncthreads();
    if (tid < 128) {
        float s = 0.f;
        #pragma unroll
        for (int c = 0; c < 2; ++c)
            #pragma unroll
            for (int ky = 0; ky < 7; ++ky)
                #pragma unroll
                for (int kx = 0; kx < 7; ++kx)
                    s += ls[c][ky][tid + kx] * lk[c * 49 + ky * 7 + kx];
        s = s * (g[0] * rsqrtf(1.0f + 1e-5f)) + bb[0];
        sws[tid] = 1.0f / (1.0f + expf(-s));
    }
    __syncthreads();
    // apply: out[b][o][h][:] = h2f(outi)*scw[o]*sws[:] + x, coalesced rows
    int w4 = tid & 31, og = tid >> 5;
    long base = (((long)b << 21) + (h << 7)) + (w4 << 2);
    float4_t sv = *(const float4_t*)&sws[w4 << 2];
    #pragma unroll
    for (int o = og; o < 128; o += 8) {
        long idx = base + ((long)o << 14);
        ushort4_t hv = *(const ushort4_t*)&outi[idx];
        float4_t ov = (float4_t){h2f(hv[0]), h2f(hv[1]), h2f(hv[2]), h2f(hv[3])};
        float4_t xv = *(const float4_t*)&x[idx];
        float4_t r = ov * scw[o] * sv + xv;
        *(float4_t*)&out[idx] = r;
    }
}

extern "C" void kernel_launch(void* const* d_in, const int* in_sizes, int n_in,
                              void* d_out, int out_size, void* d_ws, size_t ws_size,
                              hipStream_t stream) {
    const float* x       = (const float*)d_in[0];
    const float* experts = (const float*)d_in[1];
    const float* rw1     = (const float*)d_in[2];
    const float* rbn1_g  = (const float*)d_in[3];
    const float* rbn1_b  = (const float*)d_in[4];
    const float* rw2     = (const float*)d_in[5];
    const float* rbn2_g  = (const float*)d_in[6];
    const float* rbn2_b  = (const float*)d_in[7];
    const float* rw3     = (const float*)d_in[8];
    const float* rb3     = (const float*)d_in[9];
    const float* ca_w1   = (const float*)d_in[10];
    const float* ca_bn1g = (const float*)d_in[11];
    const float* ca_bn1b = (const float*)d_in[12];
    const float* ca_w2   = (const float*)d_in[13];
    const float* ca_bn2g = (const float*)d_in[14];
    const float* ca_bn2b = (const float*)d_in[15];
    const float* sa_w    = (const float*)d_in[16];
    const float* sa_g    = (const float*)d_in[17];
    const float* sa_b    = (const float*)d_in[18];
    float* out = (float*)d_out;
    char* ws = (char*)d_ws;

    ushort_t* xn   = (ushort_t*)(ws);
    ushort_t* w2   = (ushort_t*)(ws + 69222400);
    float*    p    = (float*)(ws + 73940992);
    float*    cp   = (float*)(ws + 73949184);
    float*    cw   = (float*)(ws + 73958400);
    float*    sp   = (float*)(ws + 73966592);
    ushort_t* outi = (ushort_t*)(ws + 76264960);

    hipLaunchKernelGGL(init_kernel, dim3(6389), dim3(256), 0, stream, p, cp, sp, xn);
    hipLaunchKernelGGL(transpose_kernel, dim3(4096), dim3(256), 0, stream, x, xn, p);
    hipLaunchKernelGGL(wgen_kernel, dim3(128), dim3(256), 0, stream,
                       experts, p, rw1, rbn1_g, rbn1_b, rw2, rbn2_g, rbn2_b, rw3, rb3, w2);
    hipLaunchKernelGGL(conv_kernel, dim3(2048), dim3(256), 0, stream, xn, w2, outi, cp);
    hipLaunchKernelGGL(stat_kernel, dim3(2048), dim3(256), 0, stream,
                       outi, cp, ca_w1, ca_bn1g, ca_bn1b, ca_w2, ca_bn2g, ca_bn2b, cw, sp);
    hipLaunchKernelGGL(sattn_kernel, dim3(2048), dim3(256), 0, stream,
                       sp, sa_w, sa_g, sa_b, cw, x, outi, out);
}